// Round 7
// baseline (2245.195 us; speedup 1.0000x reference)
//
#include <hip/hip_runtime.h>
#include <hip/hip_fp16.h>
#include <stdint.h>
#include <type_traits>

// ClockworkRNN MI355X round 7.
// R6's role remap + all-register weights, with the two UNVERIFIED elements
// replaced by R4-verified forms: scalar h2 LDS loads (no u32x4 aliasing) and
// __shfl_xor reductions (no permlane builtins).
//   Group A (waves 0-3): m0 every step, m3 /8, m6 /64, m7 /128  (128 wreg)
//   Group B (waves 4-7): m1 /2, m2 /4, m4 /16, m5 /32           (160 wreg)
// Each module: 16 cols x 4 K-chunks across the wave (lanes {l,l^16,l^32,l^48}
// share column l&15 of wave-quarter); h reads are wave-broadcast per chunk.
// Double-buffered h + one relaxed (lgkm-only) barrier per step; fast tanh.
// ws layout (bytes): [0, 67108864) X f16 | [67108864, 67371008) W^T f16 |
//                    [67371008, 100794368) compact x f16.

typedef _Float16 half_t;
typedef _Float16 h2 __attribute__((ext_vector_type(2)));
typedef _Float16 h8 __attribute__((ext_vector_type(8)));
typedef float f4 __attribute__((ext_vector_type(4)));

__device__ __forceinline__ float dot2f(h2 a, h2 b, float c) {
#if defined(__has_builtin)
#if __has_builtin(__builtin_amdgcn_fdot2)
  return __builtin_amdgcn_fdot2(a, b, c, false);
#else
  return c + (float)a[0] * (float)b[0] + (float)a[1] * (float)b[1];
#endif
#else
  return c + (float)a[0] * (float)b[0] + (float)a[1] * (float)b[1];
#endif
}

__device__ __forceinline__ float fast_tanh(float x) {
#if defined(__has_builtin)
#if __has_builtin(__builtin_amdgcn_exp2f) && __has_builtin(__builtin_amdgcn_rcpf)
  float e = __builtin_amdgcn_exp2f(x * 2.885390081777927f);
  return 1.0f - 2.0f * __builtin_amdgcn_rcpf(e + 1.0f);
#else
  float e = __builtin_exp2f(x * 2.885390081777927f);
  return 1.0f - 2.0f / (e + 1.0f);
#endif
#else
  float e = exp2f(x * 2.885390081777927f);
  return 1.0f - 2.0f / (e + 1.0f);
#endif
}

// Relaxed workgroup barrier: orders LDS (lgkm) but leaves global loads in flight.
__device__ __forceinline__ void wg_barrier_lds() {
  __builtin_amdgcn_sched_barrier(0);
  asm volatile("s_waitcnt lgkmcnt(0)" ::: "memory");
  __builtin_amdgcn_s_barrier();
  __builtin_amdgcn_sched_barrier(0);
}

__device__ __forceinline__ void gl_lds16(const half_t* g, half_t* l) {
  __builtin_amdgcn_global_load_lds(
      (__attribute__((address_space(1))) void*)(void*)g,
      (__attribute__((address_space(3))) void*)(void*)l, 16, 0, 0);
}

// ---------------- cvt kernels (unchanged, verified) ----------------
__global__ void cw_cvt_x(const float* __restrict__ X, half_t* __restrict__ Xh, long n4) {
  long i = (long)blockIdx.x * blockDim.x + threadIdx.x;
  const long stride = (long)gridDim.x * blockDim.x;
  const float4* X4 = (const float4*)X;
  h2* out2 = (h2*)Xh;
  for (; i < n4; i += stride) {
    float4 v = X4[i];
    h2 a; a[0] = (half_t)v.x; a[1] = (half_t)v.y;
    h2 b; b[0] = (half_t)v.z; b[1] = (half_t)v.w;
    out2[2 * i] = a;
    out2[2 * i + 1] = b;
  }
}

__global__ void cw_cvt_wt(const float* __restrict__ W, half_t* __restrict__ WT) {
  int idx = blockIdx.x * 256 + threadIdx.x;  // 131072 total
  int o = idx >> 8, d = idx & 255;
  WT[idx] = (half_t)W[d * 512 + o];
}

// ---------------- x projection (unchanged, verified) ----------------
__global__ __launch_bounds__(256) void cw_xproj(const half_t* __restrict__ Xh,
                                                const half_t* __restrict__ WT,
                                                const float* __restrict__ bias,
                                                half_t* __restrict__ xout) {
  const int mod = blockIdx.y;
  const int Ti = 2048 >> mod;
  const long Mi = (long)64 * Ti;
  const long m0r = (long)blockIdx.x * 256;
  if (m0r >= Mi) return;
  __shared__ alignas(16) half_t Bs[64 * 256];
  __shared__ alignas(16) half_t As[256 * 64];
  const int tid = threadIdx.x;
  const int wv = tid >> 6, l = tid & 63;
  const int lr = l & 15, lk = (l >> 4) * 8;
  const int shf = 11 - mod;

#pragma unroll
  for (int it = 0; it < 8; ++it) {
    int slot = it * 256 + tid;
    int n = slot >> 5, kc = slot & 31;
    gl_lds16(WT + ((mod << 6) + n) * 256 + kc * 8, Bs + slot * 8);
  }

  f4 acc[4][4];
#pragma unroll
  for (int a = 0; a < 4; ++a)
#pragma unroll
    for (int bq = 0; bq < 4; ++bq) acc[a][bq] = f4{0.f, 0.f, 0.f, 0.f};

  for (int kt = 0; kt < 4; ++kt) {
#pragma unroll
    for (int it = 0; it < 8; ++it) {
      int slot = it * 256 + tid;
      int r = slot >> 3, kc = slot & 7;
      long m = m0r + r;
      long g = (m >> shf) * 2048 + ((m & (long)(Ti - 1)) << mod);
      gl_lds16(Xh + g * 256 + kt * 64 + kc * 8, As + slot * 8);
    }
    __syncthreads();
#pragma unroll
    for (int ks = 0; ks < 2; ++ks) {
      h8 af[4], bf[4];
#pragma unroll
      for (int mi = 0; mi < 4; ++mi)
        af[mi] = *(const h8*)&As[(wv * 64 + mi * 16 + lr) * 64 + ks * 32 + lk];
#pragma unroll
      for (int ni = 0; ni < 4; ++ni)
        bf[ni] = *(const h8*)&Bs[(ni * 16 + lr) * 256 + kt * 64 + ks * 32 + lk];
#pragma unroll
      for (int mi = 0; mi < 4; ++mi)
#pragma unroll
        for (int ni = 0; ni < 4; ++ni)
          acc[mi][ni] = __builtin_amdgcn_mfma_f32_16x16x32_f16(af[mi], bf[ni], acc[mi][ni], 0, 0, 0);
    }
    __syncthreads();
  }

  const long xb = 16777216L - (16777216L >> mod);
#pragma unroll
  for (int ni = 0; ni < 4; ++ni) {
    int n = ni * 16 + lr;
    float bv = bias[(mod << 6) + n];
#pragma unroll
    for (int mi = 0; mi < 4; ++mi) {
      f4 cf = acc[mi][ni];
#pragma unroll
      for (int q = 0; q < 4; ++q) {
        long m = m0r + wv * 64 + mi * 16 + (l >> 4) * 4 + q;
        xout[xb + m * 64 + n] = (half_t)(cf[q] + bv);
      }
    }
  }
}

// ---------------- scan round 7 ----------------
// DOTW: P4 pairs/lane at h2 base HB + q*P4, weights at wreg[WB..WB+P4).
// Scalar h2 loads (clang merges adjacent pairs); static wreg indices.
#define DOTW(P4, HB, WB, OUTV)                                      \
  do {                                                              \
    const h2* hp = hin2 + (HB) + q * (P4);                          \
    float a0 = 0.f, a1 = 0.f, a2 = 0.f, a3 = 0.f;                   \
    _Pragma("unroll") for (int p = 0; p < (P4); p += 4) {           \
      a0 = dot2f(hp[p + 0], wreg[(WB) + p + 0], a0);                \
      a1 = dot2f(hp[p + 1], wreg[(WB) + p + 1], a1);                \
      a2 = dot2f(hp[p + 2], wreg[(WB) + p + 2], a2);                \
      a3 = dot2f(hp[p + 3], wreg[(WB) + p + 3], a3);                \
    }                                                               \
    OUTV = (a0 + a1) + (a2 + a3);                                   \
  } while (0)

__global__ __launch_bounds__(512, 2) void cw_scan7(
    const half_t* __restrict__ xbuf,
    const float* __restrict__ Wc0, const float* __restrict__ Wc1,
    const float* __restrict__ Wc2, const float* __restrict__ Wc3,
    const float* __restrict__ Wc4, const float* __restrict__ Wc5,
    const float* __restrict__ Wc6, const float* __restrict__ Wc7,
    float* __restrict__ out) {
  const int b = blockIdx.x;
  const int tid = threadIdx.x;
  const int wv = tid >> 6;
  const int l = tid & 63;
  const int q = l >> 4;                      // K-chunk 0..3
  const int c = ((wv & 3) << 4) + (l & 15);  // module-local column 0..63
  const bool grpA = (wv < 4);

  __shared__ alignas(16) half_t hbuf[2][512];

  h2 wreg[160];
#pragma unroll
  for (int p = 0; p < 160; ++p) wreg[p] = h2{(half_t)0.f, (half_t)0.f};

  // ---- weight init (all registers; static wreg indices) ----
  if (grpA) {
    // m0: rotated by 2q groups (R4-verified): wreg[4g+j] <- pair q*64+((g+2q)&15)*4+j
#pragma unroll
    for (int g = 0; g < 16; ++g) {
      const int gg = (g + 2 * q) & 15;
#pragma unroll
      for (int j = 0; j < 4; ++j) {
        int pr = (q << 6) + gg * 4 + j;
        wreg[4 * g + j] = h2{(half_t)Wc0[(2 * pr) * 64 + c], (half_t)Wc0[(2 * pr + 1) * 64 + c]};
      }
    }
#pragma unroll
    for (int p = 0; p < 40; ++p) {  // m3
      int pr = q * 40 + p;
      wreg[64 + p] = h2{(half_t)Wc3[(2 * pr) * 64 + c], (half_t)Wc3[(2 * pr + 1) * 64 + c]};
    }
#pragma unroll
    for (int p = 0; p < 16; ++p) {  // m6
      int pr = q * 16 + p;
      wreg[104 + p] = h2{(half_t)Wc6[(2 * pr) * 64 + c], (half_t)Wc6[(2 * pr + 1) * 64 + c]};
    }
#pragma unroll
    for (int p = 0; p < 8; ++p) {  // m7
      int pr = q * 8 + p;
      wreg[120 + p] = h2{(half_t)Wc7[(2 * pr) * 64 + c], (half_t)Wc7[(2 * pr + 1) * 64 + c]};
    }
  } else {
#pragma unroll
    for (int p = 0; p < 56; ++p) {  // m1
      int pr = q * 56 + p;
      wreg[p] = h2{(half_t)Wc1[(2 * pr) * 64 + c], (half_t)Wc1[(2 * pr + 1) * 64 + c]};
    }
#pragma unroll
    for (int p = 0; p < 48; ++p) {  // m2
      int pr = q * 48 + p;
      wreg[56 + p] = h2{(half_t)Wc2[(2 * pr) * 64 + c], (half_t)Wc2[(2 * pr + 1) * 64 + c]};
    }
#pragma unroll
    for (int p = 0; p < 32; ++p) {  // m4
      int pr = q * 32 + p;
      wreg[104 + p] = h2{(half_t)Wc4[(2 * pr) * 64 + c], (half_t)Wc4[(2 * pr + 1) * 64 + c]};
    }
#pragma unroll
    for (int p = 0; p < 24; ++p) {  // m5
      int pr = q * 24 + p;
      wreg[136 + p] = h2{(half_t)Wc5[(2 * pr) * 64 + c], (half_t)Wc5[(2 * pr + 1) * 64 + c]};
    }
  }

  hbuf[0][tid] = (half_t)0.f;
  hbuf[1][tid] = (half_t)0.f;

  // ---- x pointers (compact layout, bases in halves) ----
  const half_t *xpP, *xpQ, *xpR, *xpS;
  if (grpA) {
    xpP = xbuf + ((long)b << 17) + c;              // m0
    xpQ = xbuf + 14680064L + ((long)b << 14) + c;  // m3
    xpR = xbuf + 16515072L + ((long)b << 11) + c;  // m6
    xpS = xbuf + 16646144L + ((long)b << 10) + c;  // m7
  } else {
    xpP = xbuf + 8388608L + ((long)b << 16) + c;   // m1
    xpQ = xbuf + 12582912L + ((long)b << 15) + c;  // m2
    xpR = xbuf + 15728640L + ((long)b << 13) + c;  // m4
    xpS = xbuf + 16252928L + ((long)b << 12) + c;  // m5
  }

  float hsP = 0.f, hsQ = 0.f, hsR = 0.f, hsS = 0.f;
  float xr0 = 0.f, xr1 = 0.f, xr2 = 0.f, xr3 = 0.f;
  float xrQ = 0.f, xrR = 0.f, xrS = 0.f;
  if (l < 16) {
    if (grpA) {
      xr0 = (float)xpP[0];
      xr1 = (float)xpP[64];
      xr2 = (float)xpP[128];
      xr3 = (float)xpP[192];
    } else {
      xr0 = (float)xpP[0];   // m1 row 0 (t=0)
      xr1 = (float)xpP[64];  // m1 row 1 (t=2)
    }
    xrQ = (float)xpQ[0];
    xrR = (float)xpR[0];
    xrS = (float)xpS[0];
  }
  __syncthreads();

  auto step = [&](auto offc, int t, const half_t* hin, half_t* hout) {
    constexpr int OFF = decltype(offc)::value;
    const h2* hin2 = (const h2*)hin;
    if (grpA) {
      // ---- m0 every step (R4-verified body) ----
      float v0;
      {
        const h2* hp = hin2 + (q << 6);
        float a0 = 0.f, a1 = 0.f, a2 = 0.f, a3 = 0.f;
#pragma unroll
        for (int g = 0; g < 16; ++g) {
          const int gg = (g + 2 * q) & 15;  // runtime LDS index only
          a0 = dot2f(hp[gg * 4 + 0], wreg[4 * g + 0], a0);
          a1 = dot2f(hp[gg * 4 + 1], wreg[4 * g + 1], a1);
          a2 = dot2f(hp[gg * 4 + 2], wreg[4 * g + 2], a2);
          a3 = dot2f(hp[gg * 4 + 3], wreg[4 * g + 3], a3);
        }
        v0 = (a0 + a1) + (a2 + a3);
      }
      v0 += __shfl_xor(v0, 16);
      v0 += __shfl_xor(v0, 32);
      const bool u3 = (OFF == 0) && ((t & 7) == 0);
      const bool u6 = (OFF == 0) && ((t & 63) == 0);
      const bool u7 = (OFF == 0) && ((t & 127) == 0);
      float v3 = 0.f, v6 = 0.f, v7 = 0.f;
      if (u3) { DOTW(40, 96, 64, v3); v3 += __shfl_xor(v3, 16); v3 += __shfl_xor(v3, 32); }
      if (u6) { DOTW(16, 192, 104, v6); v6 += __shfl_xor(v6, 16); v6 += __shfl_xor(v6, 32); }
      if (u7) { DOTW(8, 224, 120, v7); v7 += __shfl_xor(v7, 16); v7 += __shfl_xor(v7, 32); }
      if (l < 16) {
        // m0
        float xv;
        if constexpr (OFF == 0) xv = xr0;
        else if constexpr (OFF == 1) xv = xr1;
        else if constexpr (OFF == 2) xv = xr2;
        else xv = xr3;
        hsP = fast_tanh(v0 + xv);
        hout[c] = (half_t)hsP;
        int tn = t + OFF + 4;
        if (tn < 2048) {
          float nv = (float)xpP[(long)tn << 6];
          if constexpr (OFF == 0) xr0 = nv;
          else if constexpr (OFF == 1) xr1 = nv;
          else if constexpr (OFF == 2) xr2 = nv;
          else xr3 = nv;
        }
        // m3 (period 8)
        if (u3) {
          hsQ = fast_tanh(v3 + xrQ);
          int ni = (t >> 3) + 1;
          if (ni < 256) xrQ = (float)xpQ[(long)ni << 6];
        } else {
          hsQ = fast_tanh(hsQ);
        }
        hout[192 + c] = (half_t)hsQ;
        // m6 (period 64)
        if (u6) {
          hsR = fast_tanh(v6 + xrR);
          int ni = (t >> 6) + 1;
          if (ni < 32) xrR = (float)xpR[(long)ni << 6];
        } else {
          hsR = fast_tanh(hsR);
        }
        hout[384 + c] = (half_t)hsR;
        // m7 (period 128)
        if (u7) {
          hsS = fast_tanh(v7 + xrS);
          int ni = (t >> 7) + 1;
          if (ni < 16) xrS = (float)xpS[(long)ni << 6];
        } else {
          hsS = fast_tanh(hsS);
        }
        hout[448 + c] = (half_t)hsS;
      }
    } else {
      const bool u4 = (OFF == 0) && ((t & 15) == 0);
      const bool u5 = (OFF == 0) && ((t & 31) == 0);
      float v1 = 0.f, v2 = 0.f, v4 = 0.f, v5 = 0.f;
      if constexpr ((OFF & 1) == 0) {
        DOTW(56, 32, 0, v1);
        v1 += __shfl_xor(v1, 16);
        v1 += __shfl_xor(v1, 32);
      }
      if constexpr (OFF == 0) {
        DOTW(48, 64, 56, v2);
        v2 += __shfl_xor(v2, 16);
        v2 += __shfl_xor(v2, 32);
      }
      if (u4) { DOTW(32, 128, 104, v4); v4 += __shfl_xor(v4, 16); v4 += __shfl_xor(v4, 32); }
      if (u5) { DOTW(24, 160, 136, v5); v5 += __shfl_xor(v5, 16); v5 += __shfl_xor(v5, 32); }
      if (l < 16) {
        // m1 (period 2)
        if constexpr ((OFF & 1) == 0) {
          float xv = (OFF == 0) ? xr0 : xr1;
          hsP = fast_tanh(v1 + xv);
          int rn = ((t + OFF) >> 1) + 2;
          if (rn < 1024) {
            float nv = (float)xpP[(long)rn << 6];
            if constexpr (OFF == 0) xr0 = nv;
            else xr1 = nv;
          }
        } else {
          hsP = fast_tanh(hsP);
        }
        hout[64 + c] = (half_t)hsP;
        // m2 (period 4)
        if constexpr (OFF == 0) {
          hsQ = fast_tanh(v2 + xrQ);
          int ni = (t >> 2) + 1;
          if (ni < 512) xrQ = (float)xpQ[(long)ni << 6];
        } else {
          hsQ = fast_tanh(hsQ);
        }
        hout[128 + c] = (half_t)hsQ;
        // m4 (period 16)
        if (u4) {
          hsR = fast_tanh(v4 + xrR);
          int ni = (t >> 4) + 1;
          if (ni < 128) xrR = (float)xpR[(long)ni << 6];
        } else {
          hsR = fast_tanh(hsR);
        }
        hout[256 + c] = (half_t)hsR;
        // m5 (period 32)
        if (u5) {
          hsS = fast_tanh(v5 + xrS);
          int ni = (t >> 5) + 1;
          if (ni < 64) xrS = (float)xpS[(long)ni << 6];
        } else {
          hsS = fast_tanh(hsS);
        }
        hout[320 + c] = (half_t)hsS;
      }
    }
    wg_barrier_lds();
  };

  for (int t = 0; t < 2048; t += 4) {
    step(std::integral_constant<int, 0>{}, t, hbuf[0], hbuf[1]);
    step(std::integral_constant<int, 1>{}, t, hbuf[1], hbuf[0]);
    step(std::integral_constant<int, 2>{}, t, hbuf[0], hbuf[1]);
    step(std::integral_constant<int, 3>{}, t, hbuf[1], hbuf[0]);
  }

  // ---- output ----
  float* ob = out + ((long)b << 9);
  if (l < 16) {
    if (grpA) {
      ob[c] = hsP;
      ob[192 + c] = hsQ;
      ob[384 + c] = hsR;
      ob[448 + c] = hsS;
    } else {
      ob[64 + c] = hsP;
      ob[128 + c] = hsQ;
      ob[256 + c] = hsR;
      ob[320 + c] = hsS;
    }
  }
}

// ---------------- launcher ----------------
extern "C" void kernel_launch(void* const* d_in, const int* in_sizes, int n_in,
                              void* d_out, int out_size, void* d_ws, size_t ws_size,
                              hipStream_t stream) {
  const float* X = (const float*)d_in[0];
  const float* W = (const float*)d_in[1];
  const float* bias = (const float*)d_in[2];
  const float* Wc0 = (const float*)d_in[3];
  const float* Wc1 = (const float*)d_in[4];
  const float* Wc2 = (const float*)d_in[5];
  const float* Wc3 = (const float*)d_in[6];
  const float* Wc4 = (const float*)d_in[7];
  const float* Wc5 = (const float*)d_in[8];
  const float* Wc6 = (const float*)d_in[9];
  const float* Wc7 = (const float*)d_in[10];
  float* out = (float*)d_out;

  half_t* Xh = (half_t*)d_ws;                       // 67,108,864 B
  half_t* WT = (half_t*)((char*)d_ws + 67108864);   //    262,144 B
  half_t* xbuf = (half_t*)((char*)d_ws + 67371008); // 33,423,360 B

  cw_cvt_x<<<4096, 256, 0, stream>>>(X, Xh, 8388608L);
  cw_cvt_wt<<<512, 256, 0, stream>>>(W, WT);
  dim3 g(512, 8);
  cw_xproj<<<g, 256, 0, stream>>>(Xh, WT, bias, xbuf);
  cw_scan7<<<64, 512, 0, stream>>>(xbuf, Wc0, Wc1, Wc2, Wc3, Wc4, Wc5, Wc6, Wc7, out);
}

// Round 8
// 1677.620 us; speedup vs baseline: 1.3383x; 1.3383x over previous
//
#include <hip/hip_runtime.h>
#include <hip/hip_fp16.h>
#include <stdint.h>
#include <type_traits>

// ClockworkRNN MI355X round 8.
// R7 (verified, absmax 0.0039) + ONE change: x-prefetch loads land in RAW u16
// registers; f16->f32 conversion happens at USE (4 steps later). R1..R7 all
// fused the cvt to the load ((float)ptr[i]), forcing s_waitcnt vmcnt(0) right
// after issue -- the full HBM/L2 round trip sat inside every step's critical
// path, which is why per-step time (~2500cyc) was insensitive to all other
// structure changes.
// ws layout (bytes): [0, 67108864) X f16 | [67108864, 67371008) W^T f16 |
//                    [67371008, 100794368) compact x f16.

typedef _Float16 half_t;
typedef _Float16 h2 __attribute__((ext_vector_type(2)));
typedef _Float16 h8 __attribute__((ext_vector_type(8)));
typedef float f4 __attribute__((ext_vector_type(4)));

__device__ __forceinline__ float dot2f(h2 a, h2 b, float c) {
#if defined(__has_builtin)
#if __has_builtin(__builtin_amdgcn_fdot2)
  return __builtin_amdgcn_fdot2(a, b, c, false);
#else
  return c + (float)a[0] * (float)b[0] + (float)a[1] * (float)b[1];
#endif
#else
  return c + (float)a[0] * (float)b[0] + (float)a[1] * (float)b[1];
#endif
}

__device__ __forceinline__ float fast_tanh(float x) {
#if defined(__has_builtin)
#if __has_builtin(__builtin_amdgcn_exp2f) && __has_builtin(__builtin_amdgcn_rcpf)
  float e = __builtin_amdgcn_exp2f(x * 2.885390081777927f);
  return 1.0f - 2.0f * __builtin_amdgcn_rcpf(e + 1.0f);
#else
  float e = __builtin_exp2f(x * 2.885390081777927f);
  return 1.0f - 2.0f / (e + 1.0f);
#endif
#else
  float e = exp2f(x * 2.885390081777927f);
  return 1.0f - 2.0f / (e + 1.0f);
#endif
}

// raw u16 -> float at USE time (keeps the load untouched until here)
__device__ __forceinline__ float u2f(unsigned short u) {
  return (float)__builtin_bit_cast(half_t, u);
}

// Relaxed workgroup barrier: orders LDS (lgkm) but leaves global loads in flight.
__device__ __forceinline__ void wg_barrier_lds() {
  __builtin_amdgcn_sched_barrier(0);
  asm volatile("s_waitcnt lgkmcnt(0)" ::: "memory");
  __builtin_amdgcn_s_barrier();
  __builtin_amdgcn_sched_barrier(0);
}

__device__ __forceinline__ void gl_lds16(const half_t* g, half_t* l) {
  __builtin_amdgcn_global_load_lds(
      (__attribute__((address_space(1))) void*)(void*)g,
      (__attribute__((address_space(3))) void*)(void*)l, 16, 0, 0);
}

// ---------------- cvt kernels (unchanged, verified) ----------------
__global__ void cw_cvt_x(const float* __restrict__ X, half_t* __restrict__ Xh, long n4) {
  long i = (long)blockIdx.x * blockDim.x + threadIdx.x;
  const long stride = (long)gridDim.x * blockDim.x;
  const float4* X4 = (const float4*)X;
  h2* out2 = (h2*)Xh;
  for (; i < n4; i += stride) {
    float4 v = X4[i];
    h2 a; a[0] = (half_t)v.x; a[1] = (half_t)v.y;
    h2 b; b[0] = (half_t)v.z; b[1] = (half_t)v.w;
    out2[2 * i] = a;
    out2[2 * i + 1] = b;
  }
}

__global__ void cw_cvt_wt(const float* __restrict__ W, half_t* __restrict__ WT) {
  int idx = blockIdx.x * 256 + threadIdx.x;  // 131072 total
  int o = idx >> 8, d = idx & 255;
  WT[idx] = (half_t)W[d * 512 + o];
}

// ---------------- x projection (unchanged, verified) ----------------
__global__ __launch_bounds__(256) void cw_xproj(const half_t* __restrict__ Xh,
                                                const half_t* __restrict__ WT,
                                                const float* __restrict__ bias,
                                                half_t* __restrict__ xout) {
  const int mod = blockIdx.y;
  const int Ti = 2048 >> mod;
  const long Mi = (long)64 * Ti;
  const long m0r = (long)blockIdx.x * 256;
  if (m0r >= Mi) return;
  __shared__ alignas(16) half_t Bs[64 * 256];
  __shared__ alignas(16) half_t As[256 * 64];
  const int tid = threadIdx.x;
  const int wv = tid >> 6, l = tid & 63;
  const int lr = l & 15, lk = (l >> 4) * 8;
  const int shf = 11 - mod;

#pragma unroll
  for (int it = 0; it < 8; ++it) {
    int slot = it * 256 + tid;
    int n = slot >> 5, kc = slot & 31;
    gl_lds16(WT + ((mod << 6) + n) * 256 + kc * 8, Bs + slot * 8);
  }

  f4 acc[4][4];
#pragma unroll
  for (int a = 0; a < 4; ++a)
#pragma unroll
    for (int bq = 0; bq < 4; ++bq) acc[a][bq] = f4{0.f, 0.f, 0.f, 0.f};

  for (int kt = 0; kt < 4; ++kt) {
#pragma unroll
    for (int it = 0; it < 8; ++it) {
      int slot = it * 256 + tid;
      int r = slot >> 3, kc = slot & 7;
      long m = m0r + r;
      long g = (m >> shf) * 2048 + ((m & (long)(Ti - 1)) << mod);
      gl_lds16(Xh + g * 256 + kt * 64 + kc * 8, As + slot * 8);
    }
    __syncthreads();
#pragma unroll
    for (int ks = 0; ks < 2; ++ks) {
      h8 af[4], bf[4];
#pragma unroll
      for (int mi = 0; mi < 4; ++mi)
        af[mi] = *(const h8*)&As[(wv * 64 + mi * 16 + lr) * 64 + ks * 32 + lk];
#pragma unroll
      for (int ni = 0; ni < 4; ++ni)
        bf[ni] = *(const h8*)&Bs[(ni * 16 + lr) * 256 + kt * 64 + ks * 32 + lk];
#pragma unroll
      for (int mi = 0; mi < 4; ++mi)
#pragma unroll
        for (int ni = 0; ni < 4; ++ni)
          acc[mi][ni] = __builtin_amdgcn_mfma_f32_16x16x32_f16(af[mi], bf[ni], acc[mi][ni], 0, 0, 0);
    }
    __syncthreads();
  }

  const long xb = 16777216L - (16777216L >> mod);
#pragma unroll
  for (int ni = 0; ni < 4; ++ni) {
    int n = ni * 16 + lr;
    float bv = bias[(mod << 6) + n];
#pragma unroll
    for (int mi = 0; mi < 4; ++mi) {
      f4 cf = acc[mi][ni];
#pragma unroll
      for (int q = 0; q < 4; ++q) {
        long m = m0r + wv * 64 + mi * 16 + (l >> 4) * 4 + q;
        xout[xb + m * 64 + n] = (half_t)(cf[q] + bv);
      }
    }
  }
}

// ---------------- scan round 8 ----------------
#define DOTW(P4, HB, WB, OUTV)                                      \
  do {                                                              \
    const h2* hp = hin2 + (HB) + q * (P4);                          \
    float a0 = 0.f, a1 = 0.f, a2 = 0.f, a3 = 0.f;                   \
    _Pragma("unroll") for (int p = 0; p < (P4); p += 4) {           \
      a0 = dot2f(hp[p + 0], wreg[(WB) + p + 0], a0);                \
      a1 = dot2f(hp[p + 1], wreg[(WB) + p + 1], a1);                \
      a2 = dot2f(hp[p + 2], wreg[(WB) + p + 2], a2);                \
      a3 = dot2f(hp[p + 3], wreg[(WB) + p + 3], a3);                \
    }                                                               \
    OUTV = (a0 + a1) + (a2 + a3);                                   \
  } while (0)

__global__ __launch_bounds__(512, 2) void cw_scan8(
    const half_t* __restrict__ xbuf,
    const float* __restrict__ Wc0, const float* __restrict__ Wc1,
    const float* __restrict__ Wc2, const float* __restrict__ Wc3,
    const float* __restrict__ Wc4, const float* __restrict__ Wc5,
    const float* __restrict__ Wc6, const float* __restrict__ Wc7,
    float* __restrict__ out) {
  const int b = blockIdx.x;
  const int tid = threadIdx.x;
  const int wv = tid >> 6;
  const int l = tid & 63;
  const int q = l >> 4;                      // K-chunk 0..3
  const int c = ((wv & 3) << 4) + (l & 15);  // module-local column 0..63
  const bool grpA = (wv < 4);

  __shared__ alignas(16) half_t hbuf[2][512];

  h2 wreg[160];
#pragma unroll
  for (int p = 0; p < 160; ++p) wreg[p] = h2{(half_t)0.f, (half_t)0.f};

  // ---- weight init (all registers; static wreg indices) ----
  if (grpA) {
    // m0: rotated by 2q groups (R4-verified): wreg[4g+j] <- pair q*64+((g+2q)&15)*4+j
#pragma unroll
    for (int g = 0; g < 16; ++g) {
      const int gg = (g + 2 * q) & 15;
#pragma unroll
      for (int j = 0; j < 4; ++j) {
        int pr = (q << 6) + gg * 4 + j;
        wreg[4 * g + j] = h2{(half_t)Wc0[(2 * pr) * 64 + c], (half_t)Wc0[(2 * pr + 1) * 64 + c]};
      }
    }
#pragma unroll
    for (int p = 0; p < 40; ++p) {  // m3
      int pr = q * 40 + p;
      wreg[64 + p] = h2{(half_t)Wc3[(2 * pr) * 64 + c], (half_t)Wc3[(2 * pr + 1) * 64 + c]};
    }
#pragma unroll
    for (int p = 0; p < 16; ++p) {  // m6
      int pr = q * 16 + p;
      wreg[104 + p] = h2{(half_t)Wc6[(2 * pr) * 64 + c], (half_t)Wc6[(2 * pr + 1) * 64 + c]};
    }
#pragma unroll
    for (int p = 0; p < 8; ++p) {  // m7
      int pr = q * 8 + p;
      wreg[120 + p] = h2{(half_t)Wc7[(2 * pr) * 64 + c], (half_t)Wc7[(2 * pr + 1) * 64 + c]};
    }
  } else {
#pragma unroll
    for (int p = 0; p < 56; ++p) {  // m1
      int pr = q * 56 + p;
      wreg[p] = h2{(half_t)Wc1[(2 * pr) * 64 + c], (half_t)Wc1[(2 * pr + 1) * 64 + c]};
    }
#pragma unroll
    for (int p = 0; p < 48; ++p) {  // m2
      int pr = q * 48 + p;
      wreg[56 + p] = h2{(half_t)Wc2[(2 * pr) * 64 + c], (half_t)Wc2[(2 * pr + 1) * 64 + c]};
    }
#pragma unroll
    for (int p = 0; p < 32; ++p) {  // m4
      int pr = q * 32 + p;
      wreg[104 + p] = h2{(half_t)Wc4[(2 * pr) * 64 + c], (half_t)Wc4[(2 * pr + 1) * 64 + c]};
    }
#pragma unroll
    for (int p = 0; p < 24; ++p) {  // m5
      int pr = q * 24 + p;
      wreg[136 + p] = h2{(half_t)Wc5[(2 * pr) * 64 + c], (half_t)Wc5[(2 * pr + 1) * 64 + c]};
    }
  }

  hbuf[0][tid] = (half_t)0.f;
  hbuf[1][tid] = (half_t)0.f;

  // ---- x pointers as RAW u16 (compact layout, bases in halves) ----
  const unsigned short *xpP, *xpQ, *xpR, *xpS;
  const unsigned short* xb16 = (const unsigned short*)xbuf;
  if (grpA) {
    xpP = xb16 + ((long)b << 17) + c;              // m0
    xpQ = xb16 + 14680064L + ((long)b << 14) + c;  // m3
    xpR = xb16 + 16515072L + ((long)b << 11) + c;  // m6
    xpS = xb16 + 16646144L + ((long)b << 10) + c;  // m7
  } else {
    xpP = xb16 + 8388608L + ((long)b << 16) + c;   // m1
    xpQ = xb16 + 12582912L + ((long)b << 15) + c;  // m2
    xpR = xb16 + 15728640L + ((long)b << 13) + c;  // m4
    xpS = xb16 + 16252928L + ((long)b << 12) + c;  // m5
  }

  float hsP = 0.f, hsQ = 0.f, hsR = 0.f, hsS = 0.f;
  unsigned short xu0 = 0, xu1 = 0, xu2 = 0, xu3 = 0;
  unsigned short xuQ = 0, xuR = 0, xuS = 0;
  if (l < 16) {
    if (grpA) {
      xu0 = xpP[0];
      xu1 = xpP[64];
      xu2 = xpP[128];
      xu3 = xpP[192];
    } else {
      xu0 = xpP[0];   // m1 row 0 (t=0)
      xu1 = xpP[64];  // m1 row 1 (t=2)
    }
    xuQ = xpQ[0];
    xuR = xpR[0];
    xuS = xpS[0];
  }
  __syncthreads();

  auto step = [&](auto offc, int t, const half_t* hin, half_t* hout) {
    constexpr int OFF = decltype(offc)::value;
    const h2* hin2 = (const h2*)hin;
    if (grpA) {
      // ---- m0 every step (R4-verified body) ----
      float v0;
      {
        const h2* hp = hin2 + (q << 6);
        float a0 = 0.f, a1 = 0.f, a2 = 0.f, a3 = 0.f;
#pragma unroll
        for (int g = 0; g < 16; ++g) {
          const int gg = (g + 2 * q) & 15;  // runtime LDS index only
          a0 = dot2f(hp[gg * 4 + 0], wreg[4 * g + 0], a0);
          a1 = dot2f(hp[gg * 4 + 1], wreg[4 * g + 1], a1);
          a2 = dot2f(hp[gg * 4 + 2], wreg[4 * g + 2], a2);
          a3 = dot2f(hp[gg * 4 + 3], wreg[4 * g + 3], a3);
        }
        v0 = (a0 + a1) + (a2 + a3);
      }
      v0 += __shfl_xor(v0, 16);
      v0 += __shfl_xor(v0, 32);
      const bool u3 = (OFF == 0) && ((t & 7) == 0);
      const bool u6 = (OFF == 0) && ((t & 63) == 0);
      const bool u7 = (OFF == 0) && ((t & 127) == 0);
      float v3 = 0.f, v6 = 0.f, v7 = 0.f;
      if (u3) { DOTW(40, 96, 64, v3); v3 += __shfl_xor(v3, 16); v3 += __shfl_xor(v3, 32); }
      if (u6) { DOTW(16, 192, 104, v6); v6 += __shfl_xor(v6, 16); v6 += __shfl_xor(v6, 32); }
      if (u7) { DOTW(8, 224, 120, v7); v7 += __shfl_xor(v7, 16); v7 += __shfl_xor(v7, 32); }
      if (l < 16) {
        // m0
        float xv;
        if constexpr (OFF == 0) xv = u2f(xu0);
        else if constexpr (OFF == 1) xv = u2f(xu1);
        else if constexpr (OFF == 2) xv = u2f(xu2);
        else xv = u2f(xu3);
        hsP = fast_tanh(v0 + xv);
        hout[c] = (half_t)hsP;
        int tn = t + OFF + 4;
        if (tn < 2048) {
          unsigned short nv = xpP[(long)tn << 6];  // raw load; cvt at use
          if constexpr (OFF == 0) xu0 = nv;
          else if constexpr (OFF == 1) xu1 = nv;
          else if constexpr (OFF == 2) xu2 = nv;
          else xu3 = nv;
        }
        // m3 (period 8)
        if (u3) {
          hsQ = fast_tanh(v3 + u2f(xuQ));
          int ni = (t >> 3) + 1;
          if (ni < 256) xuQ = xpQ[(long)ni << 6];
        } else {
          hsQ = fast_tanh(hsQ);
        }
        hout[192 + c] = (half_t)hsQ;
        // m6 (period 64)
        if (u6) {
          hsR = fast_tanh(v6 + u2f(xuR));
          int ni = (t >> 6) + 1;
          if (ni < 32) xuR = xpR[(long)ni << 6];
        } else {
          hsR = fast_tanh(hsR);
        }
        hout[384 + c] = (half_t)hsR;
        // m7 (period 128)
        if (u7) {
          hsS = fast_tanh(v7 + u2f(xuS));
          int ni = (t >> 7) + 1;
          if (ni < 16) xuS = xpS[(long)ni << 6];
        } else {
          hsS = fast_tanh(hsS);
        }
        hout[448 + c] = (half_t)hsS;
      }
    } else {
      const bool u4 = (OFF == 0) && ((t & 15) == 0);
      const bool u5 = (OFF == 0) && ((t & 31) == 0);
      float v1 = 0.f, v2 = 0.f, v4 = 0.f, v5 = 0.f;
      if constexpr ((OFF & 1) == 0) {
        DOTW(56, 32, 0, v1);
        v1 += __shfl_xor(v1, 16);
        v1 += __shfl_xor(v1, 32);
      }
      if constexpr (OFF == 0) {
        DOTW(48, 64, 56, v2);
        v2 += __shfl_xor(v2, 16);
        v2 += __shfl_xor(v2, 32);
      }
      if (u4) { DOTW(32, 128, 104, v4); v4 += __shfl_xor(v4, 16); v4 += __shfl_xor(v4, 32); }
      if (u5) { DOTW(24, 160, 136, v5); v5 += __shfl_xor(v5, 16); v5 += __shfl_xor(v5, 32); }
      if (l < 16) {
        // m1 (period 2)
        if constexpr ((OFF & 1) == 0) {
          float xv = (OFF == 0) ? u2f(xu0) : u2f(xu1);
          hsP = fast_tanh(v1 + xv);
          int rn = ((t + OFF) >> 1) + 2;
          if (rn < 1024) {
            unsigned short nv = xpP[(long)rn << 6];  // raw load; cvt at use
            if constexpr (OFF == 0) xu0 = nv;
            else xu1 = nv;
          }
        } else {
          hsP = fast_tanh(hsP);
        }
        hout[64 + c] = (half_t)hsP;
        // m2 (period 4)
        if constexpr (OFF == 0) {
          hsQ = fast_tanh(v2 + u2f(xuQ));
          int ni = (t >> 2) + 1;
          if (ni < 512) xuQ = xpQ[(long)ni << 6];
        } else {
          hsQ = fast_tanh(hsQ);
        }
        hout[128 + c] = (half_t)hsQ;
        // m4 (period 16)
        if (u4) {
          hsR = fast_tanh(v4 + u2f(xuR));
          int ni = (t >> 4) + 1;
          if (ni < 128) xuR = xpR[(long)ni << 6];
        } else {
          hsR = fast_tanh(hsR);
        }
        hout[256 + c] = (half_t)hsR;
        // m5 (period 32)
        if (u5) {
          hsS = fast_tanh(v5 + u2f(xuS));
          int ni = (t >> 5) + 1;
          if (ni < 64) xuS = xpS[(long)ni << 6];
        } else {
          hsS = fast_tanh(hsS);
        }
        hout[320 + c] = (half_t)hsS;
      }
    }
    wg_barrier_lds();
  };

  for (int t = 0; t < 2048; t += 4) {
    step(std::integral_constant<int, 0>{}, t, hbuf[0], hbuf[1]);
    step(std::integral_constant<int, 1>{}, t, hbuf[1], hbuf[0]);
    step(std::integral_constant<int, 2>{}, t, hbuf[0], hbuf[1]);
    step(std::integral_constant<int, 3>{}, t, hbuf[1], hbuf[0]);
  }

  // ---- output ----
  float* ob = out + ((long)b << 9);
  if (l < 16) {
    if (grpA) {
      ob[c] = hsP;
      ob[192 + c] = hsQ;
      ob[384 + c] = hsR;
      ob[448 + c] = hsS;
    } else {
      ob[64 + c] = hsP;
      ob[128 + c] = hsQ;
      ob[256 + c] = hsR;
      ob[320 + c] = hsS;
    }
  }
}

// ---------------- launcher ----------------
extern "C" void kernel_launch(void* const* d_in, const int* in_sizes, int n_in,
                              void* d_out, int out_size, void* d_ws, size_t ws_size,
                              hipStream_t stream) {
  const float* X = (const float*)d_in[0];
  const float* W = (const float*)d_in[1];
  const float* bias = (const float*)d_in[2];
  const float* Wc0 = (const float*)d_in[3];
  const float* Wc1 = (const float*)d_in[4];
  const float* Wc2 = (const float*)d_in[5];
  const float* Wc3 = (const float*)d_in[6];
  const float* Wc4 = (const float*)d_in[7];
  const float* Wc5 = (const float*)d_in[8];
  const float* Wc6 = (const float*)d_in[9];
  const float* Wc7 = (const float*)d_in[10];
  float* out = (float*)d_out;

  half_t* Xh = (half_t*)d_ws;                       // 67,108,864 B
  half_t* WT = (half_t*)((char*)d_ws + 67108864);   //    262,144 B
  half_t* xbuf = (half_t*)((char*)d_ws + 67371008); // 33,423,360 B

  cw_cvt_x<<<4096, 256, 0, stream>>>(X, Xh, 8388608L);
  cw_cvt_wt<<<512, 256, 0, stream>>>(W, WT);
  dim3 g(512, 8);
  cw_xproj<<<g, 256, 0, stream>>>(Xh, WT, bias, xbuf);
  cw_scan8<<<64, 512, 0, stream>>>(xbuf, Wc0, Wc1, Wc2, Wc3, Wc4, Wc5, Wc6, Wc7, out);
}